// Round 5
// baseline (209.924 us; speedup 1.0000x reference)
//
#include <hip/hip_runtime.h>
#include <math.h>

#define MU_PRIOR   0.6447f
#define LOGDET_SA  4.767705615349743f   /* 3*ln(4.9) */
#define INV_SA     (1.0f/4.9f)

#define MAXGRID 2048

#define W0 (1.0f / (0.0015f  * 0.0015f))
#define W1 (1.0f / (0.0012f  * 0.0012f))
#define W2 (1.0f / (0.0010f  * 0.0010f))
#define W3 (1.0f / (0.00086f * 0.00086f))
#define W4 (1.0f / (0.00057f * 0.00057f))

/* 4-byte-aligned vector loads (row-pair offsets are 8B/4B aligned) */
typedef float f4_t __attribute__((ext_vector_type(4)));
typedef f4_t uf4 __attribute__((aligned(4)));
typedef float f2_t __attribute__((ext_vector_type(2)));
typedef f2_t uf2 __attribute__((aligned(4)));

struct R18 { f4_t a, b, c, d; f2_t e; };   /* 18 contiguous floats */
struct R10 { f4_t a, b; f2_t c; };          /* 10 contiguous floats */
struct R6  { f4_t a; f2_t b; };             /*  6 contiguous floats */

__device__ __forceinline__ R18 ld18(const float* p) {
    R18 r;
    r.a = *(const uf4*)p;        r.b = *(const uf4*)(p + 4);
    r.c = *(const uf4*)(p + 8);  r.d = *(const uf4*)(p + 12);
    r.e = *(const uf2*)(p + 16);
    return r;
}
__device__ __forceinline__ R10 ld10(const float* p) {
    R10 r;
    r.a = *(const uf4*)p; r.b = *(const uf4*)(p + 4); r.c = *(const uf2*)(p + 8);
    return r;
}
__device__ __forceinline__ R6 ld6(const float* p) {
    R6 r;
    r.a = *(const uf4*)p; r.b = *(const uf2*)(p + 4);
    return r;
}

__device__ __forceinline__ float warp_reduce_f(float v) {
#pragma unroll
    for (int off = 32; off > 0; off >>= 1) v += __shfl_down(v, off, 64);
    return v;
}

__device__ __forceinline__ double warp_reduce_d(double v) {
#pragma unroll
    for (int off = 32; off > 0; off >>= 1) v += __shfl_down(v, off, 64);
    return v;
}

/* per-row pieces (arrays indexed only by fully-unrolled constant k) */
__device__ __forceinline__ float row_terms(
    const float p[9], const float y[9], const float a[9], const float c[9],
    const float r[5], const float q[5], const float m[3])
{
    float acc = 0.f;
    float dy2 = 0.f, len = 0.f;
#pragma unroll
    for (int k = 0; k < 9; ++k) {
        const float d = p[k] - y[k];
        dy2 += d * d;
        len += (a[k] == a[k]) ? 1.f : 0.f;
    }
    acc += 10.0f * dy2 / len;

    const float tr  = c[0] + c[4] + c[8];
    const float det = c[0] * (c[4] * c[8] - c[5] * c[7])
                    - c[1] * (c[3] * c[8] - c[5] * c[6])
                    + c[2] * (c[3] * c[7] - c[4] * c[6]);
    acc += 0.5f * (LOGDET_SA - __logf(det) + tr * INV_SA);

    const float W[5] = {W0, W1, W2, W3, W4};
    float ra = 0.f;
#pragma unroll
    for (int k = 0; k < 5; ++k) {
        const float d = r[k] - q[k];
        ra += d * d * W[k];
    }
    acc += ra * 0.2f;

    float dm = 0.f;
#pragma unroll
    for (int k = 0; k < 3; ++k) {
        const float d = m[k] - MU_PRIOR;
        dm += d * d;
    }
    acc += dm * (1.0f / 29.4f);
    return acc;
}

/* Single-shot max-concurrency probe: 2 consecutive rows per thread, grid
 * sized so the grid-stride loop runs EXACTLY ONCE per thread for N=1e6.
 * Every thread's entire lifetime of loads (28 instrs, 392 B) is issued as
 * one burst ahead of its compute; there is no inter-iteration dependence,
 * no LDS, no barrier, no drain anywhere in the loop. This is the last
 * untested structural class after r0/r3/r4 all pinned at 74 us. */
__global__ __launch_bounds__(256) void loss_main(
    const float* __restrict__ pred, const float* __restrict__ yobs,
    const float* __restrict__ rrs,  const float* __restrict__ rrsp,
    const float* __restrict__ nanarr, const float* __restrict__ cov,
    const float* __restrict__ mu, double* __restrict__ partial, int pairs)
{
    const int t0     = blockIdx.x * 256 + threadIdx.x;
    const int stride = (int)gridDim.x * 256;

    float acc = 0.0f;

#pragma unroll 1
    for (int t = t0; t < pairs; t += stride) {
        const size_t b9 = 18ull * (size_t)t;   /* 9 * (2t) */
        const size_t b5 = 10ull * (size_t)t;
        const size_t b3 =  6ull * (size_t)t;

        /* ---- the whole burst: 28 independent loads ---- */
        const R18 P = ld18(pred   + b9);
        const R18 Y = ld18(yobs   + b9);
        const R18 A = ld18(nanarr + b9);
        const R18 C = ld18(cov    + b9);
        const R10 R = ld10(rrs    + b5);
        const R10 Q = ld10(rrsp   + b5);
        const R6  M = ld6 (mu     + b3);

        /* ---- row 0 (floats 0..8 of each 18-block) ---- */
        {
            const float p[9] = {P.a.x,P.a.y,P.a.z,P.a.w,P.b.x,P.b.y,P.b.z,P.b.w,P.c.x};
            const float y[9] = {Y.a.x,Y.a.y,Y.a.z,Y.a.w,Y.b.x,Y.b.y,Y.b.z,Y.b.w,Y.c.x};
            const float a[9] = {A.a.x,A.a.y,A.a.z,A.a.w,A.b.x,A.b.y,A.b.z,A.b.w,A.c.x};
            const float c[9] = {C.a.x,C.a.y,C.a.z,C.a.w,C.b.x,C.b.y,C.b.z,C.b.w,C.c.x};
            const float r[5] = {R.a.x,R.a.y,R.a.z,R.a.w,R.b.x};
            const float q[5] = {Q.a.x,Q.a.y,Q.a.z,Q.a.w,Q.b.x};
            const float m[3] = {M.a.x,M.a.y,M.a.z};
            acc += row_terms(p, y, a, c, r, q, m);
        }
        /* ---- row 1 (floats 9..17) ---- */
        {
            const float p[9] = {P.c.y,P.c.z,P.c.w,P.d.x,P.d.y,P.d.z,P.d.w,P.e.x,P.e.y};
            const float y[9] = {Y.c.y,Y.c.z,Y.c.w,Y.d.x,Y.d.y,Y.d.z,Y.d.w,Y.e.x,Y.e.y};
            const float a[9] = {A.c.y,A.c.z,A.c.w,A.d.x,A.d.y,A.d.z,A.d.w,A.e.x,A.e.y};
            const float c[9] = {C.c.y,C.c.z,C.c.w,C.d.x,C.d.y,C.d.z,C.d.w,C.e.x,C.e.y};
            const float r[5] = {R.b.y,R.b.z,R.b.w,R.c.x,R.c.y};
            const float q[5] = {Q.b.y,Q.b.z,Q.b.w,Q.c.x,Q.c.y};
            const float m[3] = {M.a.w,M.b.x,M.b.y};
            acc += row_terms(p, y, a, c, r, q, m);
        }
    }

    /* ---- block reduction -> double partial ---- */
    acc = warp_reduce_f(acc);
    __shared__ float smem[4];
    const int lane = threadIdx.x & 63;
    const int wid  = threadIdx.x >> 6;
    if (lane == 0) smem[wid] = acc;
    __syncthreads();
    if (threadIdx.x == 0)
        partial[blockIdx.x] = (double)(smem[0] + smem[1] + smem[2] + smem[3]);
}

__global__ __launch_bounds__(256) void loss_final(
    const double* __restrict__ partial, int npartials,
    const float* __restrict__ params, int nparams,
    const float* __restrict__ pred, const float* __restrict__ yobs,
    const float* __restrict__ rrs,  const float* __restrict__ rrsp,
    const float* __restrict__ nanarr, const float* __restrict__ cov,
    const float* __restrict__ mu, int mainRows, int rows,
    float* __restrict__ out)
{
    double accA = 0.0;   // per-row total (un-normalized)
    double accB = 0.0;   // l2 over parameters (un-normalized)

    for (int i = threadIdx.x; i < npartials; i += 256) accA += partial[i];
    for (int i = threadIdx.x; i < nparams; i += 256) {
        const float d = params[i] - 1.0f;
        accB += (double)(d * d);
    }

    // tail row (rows odd), scalar loads (zero iterations for N=1e6)
    for (int r = mainRows + (int)threadIdx.x; r < rows; r += 256) {
        float dy2 = 0.f, len = 0.f;
        for (int i = 0; i < 9; ++i) {
            const float d = pred[9 * (size_t)r + i] - yobs[9 * (size_t)r + i];
            dy2 += d * d;
            const float v = nanarr[9 * (size_t)r + i];
            len += (v == v) ? 1.f : 0.f;
        }
        const float W[5] = {W0, W1, W2, W3, W4};
        float racc = 0.f;
        for (int i = 0; i < 5; ++i) {
            const float d = rrs[5 * (size_t)r + i] - rrsp[5 * (size_t)r + i];
            racc += d * d * W[i];
        }
        const float* m = cov + 9 * (size_t)r;
        const float tr  = m[0] + m[4] + m[8];
        const float det = m[0] * (m[4] * m[8] - m[5] * m[7])
                        - m[1] * (m[3] * m[8] - m[5] * m[6])
                        + m[2] * (m[3] * m[7] - m[4] * m[6]);
        float dm = 0.f;
        for (int i = 0; i < 3; ++i) {
            const float d = mu[3 * (size_t)r + i] - MU_PRIOR;
            dm += d * d;
        }
        accA += (double)(racc * 0.2f + 10.f * dy2 / len
                         + 0.5f * (LOGDET_SA - __logf(det) + tr * INV_SA)
                         + dm * (1.f / 29.4f));
    }

    double val = accA * (1.0 / (double)rows) + accB * (1.0 / (double)nparams);
    val = warp_reduce_d(val);
    __shared__ double sm[4];
    const int lane = threadIdx.x & 63;
    const int wid  = threadIdx.x >> 6;
    if (lane == 0) sm[wid] = val;
    __syncthreads();
    if (threadIdx.x == 0)
        out[0] = (float)(sm[0] + sm[1] + sm[2] + sm[3]);
}

extern "C" void kernel_launch(void* const* d_in, const int* in_sizes, int n_in,
                              void* d_out, int out_size, void* d_ws, size_t ws_size,
                              hipStream_t stream) {
    const float* pred   = (const float*)d_in[0];
    const float* yobs   = (const float*)d_in[1];
    const float* rrs    = (const float*)d_in[2];
    const float* rrsp   = (const float*)d_in[3];
    const float* nanarr = (const float*)d_in[4];
    const float* cov    = (const float*)d_in[5];
    const float* mu     = (const float*)d_in[6];
    const float* params = (const float*)d_in[7];
    float* out = (float*)d_out;

    const int rows     = in_sizes[0] / 9;
    const int pairs    = rows / 2;           // 500,000 for N=1e6
    const int mainRows = pairs * 2;

    int grid = (pairs + 255) / 256;          // 1954: single-shot (1 iter/thread)
    if (grid > MAXGRID) grid = MAXGRID;
    if (grid < 1) grid = 1;

    double* partial = (double*)d_ws;   // `grid` doubles, all written every call

    loss_main<<<grid, 256, 0, stream>>>(pred, yobs, rrs, rrsp, nanarr,
                                        cov, mu, partial, pairs);
    loss_final<<<1, 256, 0, stream>>>(partial, grid, params, in_sizes[7],
                                      pred, yobs, rrs, rrsp, nanarr, cov, mu,
                                      mainRows, rows, out);
}